// Round 14
// baseline (318.000 us; speedup 1.0000x reference)
//
#include <hip/hip_runtime.h>
#include <float.h>

// VQ-VAE EMA vector quantizer, MI355X (gfx950).
// inputs:  [16,64,64,64] f32 (b,c,h,w) -> N=65536 positions, d=64
// embedding: [64,1024] f32 (d,K)
//
// Lessons: R7  — cooperative grid.sync ~30-40us each; separate launches win.
//          R10 — cross-block ticket + device fences = 9x regression. Never.
//          R13 — bucket skew: per-code WORK ASSIGNMENT = serial straggler.
//          R24 — bucket skew pt.2: per-code ATOMIC ACCUMULATION dies too
//                (98 -> 784us). Balanced sorted-perm dw only.
//          R21/R22 — MFMA f16 hi/lo + exact-f32 fixup; frag-linear Ef16.
//          R23/R26 — fused score+finalize: score 99, total 226-230. PROVEN.
//          R27 — tail attack: aggregated scatter (LDS hist+rank, 1 global
//                atomic per distinct k/block) + coalesced Ef16 build:
//                total 229.7 -> 193.1. Tail theory CONFIRMED.
// R28 (this): score occupancy 16 -> 32 waves/CU. Counters: MfmaUtil 20% +
//      VALU 21% = 41% busy, Occupancy 27% -> ~58% exposed latency at 2
//      blocks/CU x 8 waves. Restructure: 1024-thr blocks (16 waves), same
//      128pos x 1024code tile, wave = 64pos x 128codes (wc 0..7, rt 0..1);
//      512 blocks x 16 = 8192 waves = 32/CU (HW max). LDS ~50KB (3/CU
//      possible, grid needs 2), VGPR ~60 <= 64. Per-(pos,code) math,
//      fixup, epilogue BITWISE identical (epilogue on tid<512, exact R23
//      indexing). 4-way merge -> 8-way. All other kernels byte-identical.
//      Predict: score 99 -> ~65-75, total 193 -> ~160-170. If score >=95:
//      serial/barrier-bound, not latency -> revert shape.

#define K 1024
#define D 64
#define NPOS 65536
#define NELEM 4194304
#define DECAYF 0.99f
#define OMDF 0.01f
#define EPSF 1e-5f
#define CCOST 0.25f
#define DELTA 0.004f

#define OFF_Q 0
#define OFF_LOSS 4194304
#define OFF_IDX 4194305
#define OFF_EMB 4259841
#define OFF_NCS 4325377
#define OFF_AVG 4326401

typedef _Float16 half4 __attribute__((ext_vector_type(4)));
typedef _Float16 half8 __attribute__((ext_vector_type(8)));
typedef float f32x4 __attribute__((ext_vector_type(4)));

// ws float layout:
// [0] loss | [64..1088) e2 | [1088..2112) cs | [2112..3136) cursor(int)
// [3136..4160) hist(int) | [4224..69760) idxi(int)
// [69760..135296) perm(u32)
// [135296..266368) Ef16 region (131072 halves = 256KB)
// [266368..331904) dwT[K][64] | [331904..397440) ET[K][64]
// [397440..) xT[n][64] (optional, 16 MB)
//
// Ef16 frag-linear layout (halves): block (kt,grt,s) of 512 halves at
//   ((kt*16+grt)*4+s)*512, lane entry = lane*8 + half*4 + j
//   (Ah 4 halves | Al 4 halves = one 16B lane chunk, coalesced).

// Tile-transpose E -> ET[K][64], fused e2, Ef16 fragment build (coalesced);
// init hist/loss/dwT (no memsets).
__global__ void __launch_bounds__(256) prep_kernel(
    const float* __restrict__ E, float* __restrict__ ET, float* __restrict__ e2,
    _Float16* __restrict__ Ef, int* __restrict__ hist,
    float* __restrict__ loss, float* __restrict__ dwT) {
    __shared__ float tile[64][65];
    __shared__ float part[4][64];
    int tid = threadIdx.x;
    int gid = blockIdx.x * 256 + tid;  // 0..4095
#pragma unroll
    for (int i = 0; i < 16; ++i) dwT[i * 4096 + gid] = 0.f;
    if (gid < K) hist[gid] = 0;
    if (gid == 0) *loss = 0.f;

    int k0 = blockIdx.x * 64;
    int kl = tid & 63;
    int cg_ = tid >> 6;  // 0..3
#pragma unroll
    for (int cc = 0; cc < 16; ++cc) {
        int c = cc * 4 + cg_;
        tile[c][kl] = E[c * K + k0 + kl];  // coalesced
    }
    __syncthreads();
    float s = 0.f;
#pragma unroll
    for (int i = 0; i < 16; ++i) {
        float v = tile[cg_ * 16 + i][kl];
        s = fmaf(v, v, s);
    }
    part[cg_][kl] = s;
#pragma unroll
    for (int i = 0; i < 16; ++i) {
        int w = i * 256 + tid;
        int k = w >> 6, c = w & 63;
        ET[(size_t)(k0 + k) * 64 + c] = tile[c][k];
    }
    // Ef16 fragment build: one coalesced 16B store per iteration.
    {
        int lane_ = tid & 63;
        int s_ = tid >> 6;        // 0..3
        int g_ = lane_ >> 4;      // 0..3
        int l15 = lane_ & 15;
        int kt = k0 >> 8;
#pragma unroll
        for (int ch = 0; ch < 4; ++ch) {
            int code_local = ch * 16 + l15;
            int code = k0 + code_local;
            int grt = (code >> 4) & 15;
            half8 hl;
#pragma unroll
            for (int j = 0; j < 4; ++j) {
                float v = tile[s_ * 16 + g_ * 4 + j][code_local];
                _Float16 h = (_Float16)v;
                hl[j] = h;
                hl[4 + j] = (_Float16)(v - (float)h);
            }
            size_t off = (size_t)((kt * 16 + grt) * 4 + s_) * 512 + (size_t)lane_ * 8;
            *(half8*)(Ef + off) = hl;
        }
    }
    __syncthreads();
    if (tid < 64) e2[k0 + tid] = part[0][tid] + part[1][tid] + part[2][tid] + part[3][tid];
}

__device__ __forceinline__ unsigned mono_f32(float s) {
    unsigned u = __float_as_uint(s);
    return (u & 0x80000000u) ? ~u : (u | 0x80000000u);
}

// R28 fused score+finalize: 1024 thr = 16 waves (wp = w>>3 in 0..1,
// wc = w&7 in 0..7). Block = 128 pos x all 1024 codes; wave = 64 pos x
// 128 codes (rt 0..1, grt = wc*2+rt). 8192 waves total = 32/CU.
// A-frags from L2-resident Ef16; x staged once in LDS (f32, reused by
// epilogue). MFMA kt-loop barrier-free. Epilogue (tid<512): exact R23.
__global__ void __launch_bounds__(1024, 6) score_kernel(
    const float* __restrict__ in, const _Float16* __restrict__ Ef,
    const float* __restrict__ ET, const float* __restrict__ e2,
    float* __restrict__ out, int* __restrict__ idxi, float* __restrict__ xT,
    float* __restrict__ loss, int* __restrict__ hist) {
    __shared__ __align__(16) float xf[64 * 132];   // [chan][pos 128] padded, 33.8KB
    __shared__ float e2s[1024];
    __shared__ float mgb[128][8];
    __shared__ int   mgi[128][8];
    __shared__ float mgs[128][8];
    __shared__ int s_kk[128];
    __shared__ int s_fl[128];
    __shared__ int s_nf;

    int tid = threadIdx.x;
    int lane = tid & 63;
    int w = tid >> 6;  // 0..15
    int wp = w >> 3;   // 0..1
    int wc = w & 7;    // 0..7
    int g = lane >> 4; // 0..3
    int c16 = lane & 15;

    int n0 = blockIdx.x * 128;
    int b = n0 >> 12;
    int r0 = n0 & 4095;

    if (tid == 0) s_nf = 0;

    // stage x f32 tile [64 chan][128 pos]
#pragma unroll
    for (int it = 0; it < 2; ++it) {
        int idx = it * 1024 + tid;   // 0..2047
        int c = idx >> 5;
        int q = idx & 31;
        float4 v = *(const float4*)(in + (size_t)b * 262144 + c * 4096 + r0 + q * 4);
        *(float4*)(&xf[c * 132 + q * 4]) = v;
    }
    e2s[tid] = e2[tid];
    __syncthreads();

    // persistent x fragments (B operand): k=(lane>>4)*4+j+s*16, col=pos
    half4 Bh[4][4], Bl[4][4];   // [pt][s]
#pragma unroll
    for (int pt = 0; pt < 4; ++pt) {
        int p = wp * 64 + pt * 16 + c16;
#pragma unroll
        for (int s = 0; s < 4; ++s) {
            half4 hh, ll;
#pragma unroll
            for (int j = 0; j < 4; ++j) {
                float v = xf[(g * 4 + j + s * 16) * 132 + p];
                _Float16 h = (_Float16)v;
                hh[j] = h;
                ll[j] = (_Float16)(v - (float)h);
            }
            Bh[pt][s] = hh; Bl[pt][s] = ll;
        }
    }

    float best[4], sec[4]; int bk[4];
#pragma unroll
    for (int pt = 0; pt < 4; ++pt) { best[pt] = FLT_MAX; sec[pt] = FLT_MAX; bk[pt] = 0; }

    for (int kt = 0; kt < 4; ++kt) {
#pragma unroll
        for (int rt = 0; rt < 2; ++rt) {
            int grt = wc * 2 + rt;
            f32x4 acc[4];
#pragma unroll
            for (int pt = 0; pt < 4; ++pt) acc[pt] = {0.f, 0.f, 0.f, 0.f};
#pragma unroll
            for (int s = 0; s < 4; ++s) {
                const _Float16* eb = Ef + (size_t)((kt * 16 + grt) * 4 + s) * 512 + lane * 8;
                half4 Ah = *(const half4*)eb;
                half4 Al = *(const half4*)(eb + 4);
#pragma unroll
                for (int pt = 0; pt < 4; ++pt)
                    acc[pt] = __builtin_amdgcn_mfma_f32_16x16x16f16(Ah, Bh[pt][s], acc[pt], 0, 0, 0);
#pragma unroll
                for (int pt = 0; pt < 4; ++pt)
                    acc[pt] = __builtin_amdgcn_mfma_f32_16x16x16f16(Ah, Bl[pt][s], acc[pt], 0, 0, 0);
#pragma unroll
                for (int pt = 0; pt < 4; ++pt)
                    acc[pt] = __builtin_amdgcn_mfma_f32_16x16x16f16(Al, Bh[pt][s], acc[pt], 0, 0, 0);
            }
            int cb = kt * 256 + grt * 16 + g * 4;
#pragma unroll
            for (int r = 0; r < 4; ++r) {
                float ev2 = e2s[cb + r];
                int code = cb + r;
#pragma unroll
                for (int pt = 0; pt < 4; ++pt) {
                    float sc = fmaf(-2.f, acc[pt][r], ev2);
                    if (sc < best[pt]) { sec[pt] = best[pt]; best[pt] = sc; bk[pt] = code; }
                    else sec[pt] = fminf(sec[pt], sc);
                }
            }
        }
    }

    // merge the 4 lane-groups (disjoint code ranges, same pos col)
#pragma unroll
    for (int pt = 0; pt < 4; ++pt) {
#pragma unroll
        for (int m = 16; m <= 32; m <<= 1) {
            float ob = __shfl_xor(best[pt], m);
            int obk = __shfl_xor(bk[pt], m);
            float os = __shfl_xor(sec[pt], m);
            bool take = (ob < best[pt]) || (ob == best[pt] && obk < bk[pt]);
            float ns = take ? fminf(os, best[pt]) : fminf(sec[pt], ob);
            best[pt] = take ? ob : best[pt];
            bk[pt] = take ? obk : bk[pt];
            sec[pt] = ns;
        }
        if (lane < 16) {
            int posl = wp * 64 + pt * 16 + lane;
            mgb[posl][wc] = best[pt]; mgi[posl][wc] = bk[pt]; mgs[posl][wc] = sec[pt];
        }
    }
    __syncthreads();
    if (tid < 128) {
        float bb = mgb[tid][0]; int kw = mgi[tid][0]; float ss = mgs[tid][0];
#pragma unroll
        for (int i = 1; i < 8; ++i) {
            float ob = mgb[tid][i]; int ok = mgi[tid][i]; float os = mgs[tid][i];
            bool take = (ob < bb) || (ob == bb && ok < kw);
            ss = take ? fminf(os, bb) : fminf(ss, ob);
            bb = take ? ob : bb;
            kw = take ? ok : kw;
        }
        s_kk[tid] = kw;
        if ((ss - bb) < DELTA) {
            int sl = atomicAdd(&s_nf, 1);
            s_fl[sl] = tid;
        }
    }
    __syncthreads();

    // fixup: exact f32 argmin for flagged positions; one wave per position.
    // Sequential-fmaf dot — IDENTICAL rounding to R22's fixup (proven).
    int nf = s_nf;
    for (int f0 = 0; f0 < nf; f0 += 16) {
        int f = f0 + w;
        if (f < nf) {
            int posl = s_fl[f];
            unsigned long long bkey = ~0ull;
            for (int i = 0; i < 16; ++i) {
                int c = lane + i * 64;
                const float* ep = ET + (size_t)c * 64;
                float dot = 0.f;
#pragma unroll
                for (int j = 0; j < 64; ++j) dot = fmaf(xf[j * 132 + posl], ep[j], dot);
                float sc = fmaf(-2.f, dot, e2s[c]);
                unsigned long long kq = ((unsigned long long)mono_f32(sc) << 32) | (unsigned)c;
                if (kq < bkey) bkey = kq;
            }
#pragma unroll
            for (int off = 32; off > 0; off >>= 1) {
                unsigned long long o = __shfl_down(bkey, off);
                if (o < bkey) bkey = o;
            }
            if (lane == 0) s_kk[posl] = (int)(bkey & 0x3FFull);
        }
    }
    __syncthreads();

    // epilogue (tid<512): exact R23 mapping — 32 pos-groups x 16 chan-groups
    if (tid < 512) {
        int pg = tid & 31;
        int ch4 = tid >> 5;       // 0..15
        int c0 = ch4 * 4;
        int p4 = pg * 4;
        int np = n0 + p4;

        int kk[4];
#pragma unroll
        for (int p = 0; p < 4; ++p) kk[p] = s_kk[p4 + p];

        float4 xv4[4];
#pragma unroll
        for (int c = 0; c < 4; ++c) xv4[c] = *(float4*)&xf[(c0 + c) * 132 + p4];

        float4 eg[4];
#pragma unroll
        for (int p = 0; p < 4; ++p) eg[p] = *(const float4*)(ET + (size_t)kk[p] * 64 + c0);

        float* qb = out + OFF_Q + (size_t)b * 262144 + r0;
        float sq = 0.f;
#pragma unroll
        for (int c = 0; c < 4; ++c) {
            float4 qv = make_float4(((const float*)&eg[0])[c], ((const float*)&eg[1])[c],
                                    ((const float*)&eg[2])[c], ((const float*)&eg[3])[c]);
            *(float4*)(qb + (c0 + c) * 4096 + p4) = qv;
            float d0 = qv.x - ((const float*)&xv4[c])[0];
            float d1 = qv.y - ((const float*)&xv4[c])[1];
            float d2 = qv.z - ((const float*)&xv4[c])[2];
            float d3 = qv.w - ((const float*)&xv4[c])[3];
            sq = fmaf(d0, d0, sq); sq = fmaf(d1, d1, sq);
            sq = fmaf(d2, d2, sq); sq = fmaf(d3, d3, sq);
        }

        if (xT) {
#pragma unroll
            for (int p = 0; p < 4; ++p) {
                float4 tv = make_float4(((const float*)&xv4[0])[p], ((const float*)&xv4[1])[p],
                                        ((const float*)&xv4[2])[p], ((const float*)&xv4[3])[p]);
                *(float4*)(xT + (size_t)(np + p) * 64 + c0) = tv;
            }
        }

        if (ch4 == 0) {
#pragma unroll
            for (int p = 0; p < 4; ++p) out[OFF_IDX + np + p] = (float)kk[p];
            *(int4*)(idxi + np) = make_int4(kk[0], kk[1], kk[2], kk[3]);
#pragma unroll
            for (int p = 0; p < 4; ++p) atomicAdd(&hist[kk[p]], 1);
        }

#pragma unroll
        for (int off = 32; off > 0; off >>= 1) sq += __shfl_down(sq, off);
        if (lane == 0) atomicAdd(loss, sq);
    }
}

// One block: exclusive scan of hist + EMA stage1.
__global__ void __launch_bounds__(1024) scan_kernel(
    const int* __restrict__ hist, const float* __restrict__ cluster_size,
    const float* __restrict__ loss, float* __restrict__ out,
    float* __restrict__ cs_ws, int* __restrict__ cursor) {
    int t = threadIdx.x;
    __shared__ int sc[1024];
    __shared__ float fred[1024];
    int cnt = hist[t];
    sc[t] = cnt;
    __syncthreads();
    for (int off = 1; off < 1024; off <<= 1) {
        int v = (t >= off) ? sc[t - off] : 0;
        __syncthreads();
        sc[t] += v;
        __syncthreads();
    }
    cursor[t] = sc[t] - cnt;

    float ncs = cluster_size[t] * DECAYF + OMDF * (float)cnt;
    fred[t] = ncs;
    __syncthreads();
    for (int s = 512; s > 0; s >>= 1) {
        if (t < s) fred[t] += fred[t + s];
        __syncthreads();
    }
    float nsum = fred[0];
    out[OFF_NCS + t] = ncs;
    cs_ws[t] = (ncs + EPSF) / (nsum + 1024.f * EPSF) * nsum;
    if (t == 0) out[OFF_LOSS] = CCOST * loss[0] / (float)NELEM;
}

// R27: block-aggregated scatter (Guideline 12). LDS hist+rank, one global
// atomic per distinct k per block, conflict-free perm writes.
__global__ void __launch_bounds__(256) scatter_kernel(
    const int* __restrict__ idxi, int* __restrict__ cursor,
    unsigned* __restrict__ perm) {
    __shared__ int lhist[1024];
    __shared__ int lbase[1024];
    int tid = threadIdx.x;
#pragma unroll
    for (int i = 0; i < 4; ++i) lhist[i * 256 + tid] = 0;
    __syncthreads();
    int n = blockIdx.x * 256 + tid;
    int k = idxi[n];
    int rank = atomicAdd(&lhist[k], 1);
    __syncthreads();
#pragma unroll
    for (int i = 0; i < 4; ++i) {
        int kk = i * 256 + tid;
        int c = lhist[kk];
        if (c > 0) lbase[kk] = atomicAdd(&cursor[kk], c);
    }
    __syncthreads();
    perm[lbase[k] + rank] = ((unsigned)k << 17) | (unsigned)n;  // k:10b, n:17b
}

// Balanced segmented reduction over sorted perm; wave = 32 entries.
__global__ void __launch_bounds__(256) dw_accum_kernel(
    const float* __restrict__ in, const float* __restrict__ xT,
    const unsigned* __restrict__ perm, float* __restrict__ dwT) {
    int t = threadIdx.x;
    int c = t & 63;
    int wv = t >> 6;
    int base = (blockIdx.x * 4 + wv) * 32;  // 2048 waves x 32 = 65536

    __shared__ unsigned spm[4][32];
    if (c < 32) spm[wv][c] = perm[base + c];
    __syncthreads();

    float acc = 0.f;
    unsigned cur = spm[wv][0] >> 17;
#pragma unroll 4
    for (int i = 0; i < 32; ++i) {
        unsigned e = spm[wv][i];  // broadcast
        unsigned k = e >> 17;
        unsigned n = e & 0x1FFFFu;
        if (k != cur) {  // wave-uniform
            atomicAdd(&dwT[cur * 64 + c], acc);
            acc = 0.f;
            cur = k;
        }
        if (xT) {
            acc += xT[(size_t)n * 64 + c];  // 256B contiguous per wave
        } else {
            acc += in[(size_t)(n >> 12) * 262144 + c * 4096 + (n & 4095)];
        }
    }
    atomicAdd(&dwT[cur * 64 + c], acc);
}

__global__ void __launch_bounds__(256) ema2_kernel(
    const float* __restrict__ embed_avg, const float* __restrict__ dwT,
    const float* __restrict__ cs_ws, float* __restrict__ out) {
    int i = blockIdx.x * 256 + threadIdx.x;  // i = c*K + k
    int k = i & (K - 1);
    int c = i >> 10;
    float avg = embed_avg[i] * DECAYF + OMDF * dwT[k * 64 + c];
    out[OFF_AVG + i] = avg;
    out[OFF_EMB + i] = avg / cs_ws[k];
}

extern "C" void kernel_launch(void* const* d_in, const int* in_sizes, int n_in,
                              void* d_out, int out_size, void* d_ws, size_t ws_size,
                              hipStream_t stream) {
    const float* in = (const float*)d_in[0];
    const float* E = (const float*)d_in[1];
    const float* cluster_size = (const float*)d_in[2];
    const float* embed_avg = (const float*)d_in[3];
    float* out = (float*)d_out;
    float* ws = (float*)d_ws;

    float* loss = ws;
    float* e2 = ws + 64;
    float* cs = ws + 1088;
    int* cursor = (int*)(ws + 2112);   // 1024
    int* hist = (int*)(ws + 3136);     // 1024
    int* idxi = (int*)(ws + 4224);     // 65536
    unsigned* perm = (unsigned*)(ws + 69760);  // 65536
    _Float16* Ef = (_Float16*)(ws + 135296);   // 131072 halves
    float* dwT = ws + 266368;          // 65536 ([K][64])
    float* ET = ws + 331904;           // 65536 ([K][64])
    float* xT = (ws_size >= (397440ull + 4194304ull) * 4ull) ? (ws + 397440) : nullptr;

    prep_kernel<<<K / 64, 256, 0, stream>>>(E, ET, e2, Ef, hist, loss, dwT);
    score_kernel<<<512, 1024, 0, stream>>>(in, Ef, ET, e2, out, idxi, xT, loss, hist);
    scan_kernel<<<1, 1024, 0, stream>>>(hist, cluster_size, loss, out, cs, cursor);
    scatter_kernel<<<NPOS / 256, 256, 0, stream>>>(idxi, cursor, perm);
    dw_accum_kernel<<<512, 256, 0, stream>>>(in, xT, perm, dwT);
    ema2_kernel<<<D * K / 256, 256, 0, stream>>>(embed_avg, dwT, cs, out);
}

// Round 15
// 195.351 us; speedup vs baseline: 1.6278x; 1.6278x over previous
//
#include <hip/hip_runtime.h>
#include <float.h>

// VQ-VAE EMA vector quantizer, MI355X (gfx950).
// inputs:  [16,64,64,64] f32 (b,c,h,w) -> N=65536 positions, d=64
// embedding: [64,1024] f32 (d,K)
//
// Lessons: R7  — cooperative grid.sync ~30-40us each; separate launches win.
//          R10 — cross-block ticket + device fences = 9x regression. Never.
//          R13 — bucket skew: per-code WORK ASSIGNMENT = serial straggler.
//          R24 — bucket skew pt.2: per-code ATOMIC ACCUMULATION dies too
//                (98 -> 784us). Balanced sorted-perm dw only.
//          R21/R22 — MFMA f16 hi/lo + exact-f32 fixup; frag-linear Ef16.
//          R23/R26 — fused score+finalize: score 99, total 226-230.
//          R27 — aggregated scatter + coalesced Ef16 build: 193.1. PROVEN.
//          R28 — 1024-thr score for 32 waves/CU FAILED: launch_bounds cap
//                -> 40 VGPR -> B-frags spilled to scratch (FETCH 234MB,
//                WRITE 223MB phantom traffic), score 230us, total 318.
//                Score needs ~60 VGPR resident; occupancy pushes that cap
//                below that self-destruct. R27's 27% occupancy is partly
//                time-averaged — less recoverable headroom than it reads.
// R29 (this): pure REVERT to R27 (byte-identical, proven 193.1us).
//      Predict: total ~193, score ~99, VGPR 60, FETCH ~10.5MB, WRITE ~35.5MB.

#define K 1024
#define D 64
#define NPOS 65536
#define NELEM 4194304
#define DECAYF 0.99f
#define OMDF 0.01f
#define EPSF 1e-5f
#define CCOST 0.25f
#define DELTA 0.004f

#define OFF_Q 0
#define OFF_LOSS 4194304
#define OFF_IDX 4194305
#define OFF_EMB 4259841
#define OFF_NCS 4325377
#define OFF_AVG 4326401

typedef _Float16 half4 __attribute__((ext_vector_type(4)));
typedef _Float16 half8 __attribute__((ext_vector_type(8)));
typedef float f32x4 __attribute__((ext_vector_type(4)));

// ws float layout:
// [0] loss | [64..1088) e2 | [1088..2112) cs | [2112..3136) cursor(int)
// [3136..4160) hist(int) | [4224..69760) idxi(int)
// [69760..135296) perm(u32)
// [135296..266368) Ef16 region (131072 halves = 256KB)
// [266368..331904) dwT[K][64] | [331904..397440) ET[K][64]
// [397440..) xT[n][64] (optional, 16 MB)
//
// Ef16 frag-linear layout (halves): block (kt,grt,s) of 512 halves at
//   ((kt*16+grt)*4+s)*512, lane entry = lane*8 + half*4 + j
//   (Ah 4 halves | Al 4 halves = one 16B lane chunk, coalesced).

// Tile-transpose E -> ET[K][64], fused e2, Ef16 fragment build (coalesced);
// init hist/loss/dwT (no memsets).
__global__ void __launch_bounds__(256) prep_kernel(
    const float* __restrict__ E, float* __restrict__ ET, float* __restrict__ e2,
    _Float16* __restrict__ Ef, int* __restrict__ hist,
    float* __restrict__ loss, float* __restrict__ dwT) {
    __shared__ float tile[64][65];
    __shared__ float part[4][64];
    int tid = threadIdx.x;
    int gid = blockIdx.x * 256 + tid;  // 0..4095
#pragma unroll
    for (int i = 0; i < 16; ++i) dwT[i * 4096 + gid] = 0.f;
    if (gid < K) hist[gid] = 0;
    if (gid == 0) *loss = 0.f;

    int k0 = blockIdx.x * 64;
    int kl = tid & 63;
    int cg_ = tid >> 6;  // 0..3
#pragma unroll
    for (int cc = 0; cc < 16; ++cc) {
        int c = cc * 4 + cg_;
        tile[c][kl] = E[c * K + k0 + kl];  // coalesced
    }
    __syncthreads();
    float s = 0.f;
#pragma unroll
    for (int i = 0; i < 16; ++i) {
        float v = tile[cg_ * 16 + i][kl];
        s = fmaf(v, v, s);
    }
    part[cg_][kl] = s;
#pragma unroll
    for (int i = 0; i < 16; ++i) {
        int w = i * 256 + tid;
        int k = w >> 6, c = w & 63;
        ET[(size_t)(k0 + k) * 64 + c] = tile[c][k];
    }
    // Ef16 fragment build: one coalesced 16B store per iteration.
    {
        int lane_ = tid & 63;
        int s_ = tid >> 6;        // 0..3
        int g_ = lane_ >> 4;      // 0..3
        int l15 = lane_ & 15;
        int kt = k0 >> 8;
#pragma unroll
        for (int ch = 0; ch < 4; ++ch) {
            int code_local = ch * 16 + l15;
            int code = k0 + code_local;
            int grt = (code >> 4) & 15;
            half8 hl;
#pragma unroll
            for (int j = 0; j < 4; ++j) {
                float v = tile[s_ * 16 + g_ * 4 + j][code_local];
                _Float16 h = (_Float16)v;
                hl[j] = h;
                hl[4 + j] = (_Float16)(v - (float)h);
            }
            size_t off = (size_t)((kt * 16 + grt) * 4 + s_) * 512 + (size_t)lane_ * 8;
            *(half8*)(Ef + off) = hl;
        }
    }
    __syncthreads();
    if (tid < 64) e2[k0 + tid] = part[0][tid] + part[1][tid] + part[2][tid] + part[3][tid];
}

__device__ __forceinline__ unsigned mono_f32(float s) {
    unsigned u = __float_as_uint(s);
    return (u & 0x80000000u) ? ~u : (u | 0x80000000u);
}

// R23 fused score+finalize: 512 thr = 8 waves (wp 0..1, wc 0..3).
// Block = 128 pos x all 1024 codes. A-frags from L2-resident Ef16;
// x staged once in LDS (f32, reused by epilogue). MFMA kt-loop barrier-free.
// Epilogue: exact-f32 fixup for flagged, then q/loss/hist/idx/idxi/xT.
__global__ void __launch_bounds__(512, 2) score_kernel(
    const float* __restrict__ in, const _Float16* __restrict__ Ef,
    const float* __restrict__ ET, const float* __restrict__ e2,
    float* __restrict__ out, int* __restrict__ idxi, float* __restrict__ xT,
    float* __restrict__ loss, int* __restrict__ hist) {
    __shared__ __align__(16) float xf[64 * 132];   // [chan][pos 128] padded, 33.8KB
    __shared__ float e2s[1024];
    __shared__ float mgb[128][4];
    __shared__ int   mgi[128][4];
    __shared__ float mgs[128][4];
    __shared__ int s_kk[128];
    __shared__ int s_fl[128];
    __shared__ int s_nf;

    int tid = threadIdx.x;
    int lane = tid & 63;
    int w = tid >> 6;
    int wp = w >> 2;   // 0..1
    int wc = w & 3;    // 0..3
    int g = lane >> 4; // 0..3
    int c16 = lane & 15;

    int n0 = blockIdx.x * 128;
    int b = n0 >> 12;
    int r0 = n0 & 4095;

    if (tid == 0) s_nf = 0;

    // stage x f32 tile [64 chan][128 pos]
#pragma unroll
    for (int it = 0; it < 4; ++it) {
        int idx = it * 512 + tid;   // 0..2047
        int c = idx >> 5;
        int q = idx & 31;
        float4 v = *(const float4*)(in + (size_t)b * 262144 + c * 4096 + r0 + q * 4);
        *(float4*)(&xf[c * 132 + q * 4]) = v;
    }
    e2s[tid] = e2[tid];
    e2s[512 + tid] = e2[512 + tid];
    __syncthreads();

    // persistent x fragments (B operand): k=(lane>>4)*4+j+s*16, col=pos
    half4 Bh[4][4], Bl[4][4];   // [pt][s]
#pragma unroll
    for (int pt = 0; pt < 4; ++pt) {
        int p = wp * 64 + pt * 16 + c16;
#pragma unroll
        for (int s = 0; s < 4; ++s) {
            half4 hh, ll;
#pragma unroll
            for (int j = 0; j < 4; ++j) {
                float v = xf[(g * 4 + j + s * 16) * 132 + p];
                _Float16 h = (_Float16)v;
                hh[j] = h;
                ll[j] = (_Float16)(v - (float)h);
            }
            Bh[pt][s] = hh; Bl[pt][s] = ll;
        }
    }

    float best[4], sec[4]; int bk[4];
#pragma unroll
    for (int pt = 0; pt < 4; ++pt) { best[pt] = FLT_MAX; sec[pt] = FLT_MAX; bk[pt] = 0; }

    for (int kt = 0; kt < 4; ++kt) {
#pragma unroll
        for (int rt = 0; rt < 4; ++rt) {
            int grt = wc * 4 + rt;
            f32x4 acc[4];
#pragma unroll
            for (int pt = 0; pt < 4; ++pt) acc[pt] = {0.f, 0.f, 0.f, 0.f};
#pragma unroll
            for (int s = 0; s < 4; ++s) {
                const _Float16* eb = Ef + (size_t)((kt * 16 + grt) * 4 + s) * 512 + lane * 8;
                half4 Ah = *(const half4*)eb;
                half4 Al = *(const half4*)(eb + 4);
#pragma unroll
                for (int pt = 0; pt < 4; ++pt)
                    acc[pt] = __builtin_amdgcn_mfma_f32_16x16x16f16(Ah, Bh[pt][s], acc[pt], 0, 0, 0);
#pragma unroll
                for (int pt = 0; pt < 4; ++pt)
                    acc[pt] = __builtin_amdgcn_mfma_f32_16x16x16f16(Ah, Bl[pt][s], acc[pt], 0, 0, 0);
#pragma unroll
                for (int pt = 0; pt < 4; ++pt)
                    acc[pt] = __builtin_amdgcn_mfma_f32_16x16x16f16(Al, Bh[pt][s], acc[pt], 0, 0, 0);
            }
            int cb = kt * 256 + grt * 16 + g * 4;
#pragma unroll
            for (int r = 0; r < 4; ++r) {
                float ev2 = e2s[cb + r];
                int code = cb + r;
#pragma unroll
                for (int pt = 0; pt < 4; ++pt) {
                    float sc = fmaf(-2.f, acc[pt][r], ev2);
                    if (sc < best[pt]) { sec[pt] = best[pt]; best[pt] = sc; bk[pt] = code; }
                    else sec[pt] = fminf(sec[pt], sc);
                }
            }
        }
    }

    // merge the 4 lane-groups (disjoint code ranges, same pos col)
#pragma unroll
    for (int pt = 0; pt < 4; ++pt) {
#pragma unroll
        for (int m = 16; m <= 32; m <<= 1) {
            float ob = __shfl_xor(best[pt], m);
            int obk = __shfl_xor(bk[pt], m);
            float os = __shfl_xor(sec[pt], m);
            bool take = (ob < best[pt]) || (ob == best[pt] && obk < bk[pt]);
            float ns = take ? fminf(os, best[pt]) : fminf(sec[pt], ob);
            best[pt] = take ? ob : best[pt];
            bk[pt] = take ? obk : bk[pt];
            sec[pt] = ns;
        }
        if (lane < 16) {
            int posl = wp * 64 + pt * 16 + lane;
            mgb[posl][wc] = best[pt]; mgi[posl][wc] = bk[pt]; mgs[posl][wc] = sec[pt];
        }
    }
    __syncthreads();
    if (tid < 128) {
        float bb = mgb[tid][0]; int kw = mgi[tid][0]; float ss = mgs[tid][0];
#pragma unroll
        for (int i = 1; i < 4; ++i) {
            float ob = mgb[tid][i]; int ok = mgi[tid][i]; float os = mgs[tid][i];
            bool take = (ob < bb) || (ob == bb && ok < kw);
            ss = take ? fminf(os, bb) : fminf(ss, ob);
            bb = take ? ob : bb;
            kw = take ? ok : kw;
        }
        s_kk[tid] = kw;
        if ((ss - bb) < DELTA) {
            int sl = atomicAdd(&s_nf, 1);
            s_fl[sl] = tid;
        }
    }
    __syncthreads();

    // fixup: exact f32 argmin for flagged positions; one wave per position.
    // Sequential-fmaf dot — IDENTICAL rounding to R22's fixup (proven).
    int nf = s_nf;
    for (int f0 = 0; f0 < nf; f0 += 8) {
        int f = f0 + w;
        if (f < nf) {
            int posl = s_fl[f];
            unsigned long long bkey = ~0ull;
            for (int i = 0; i < 16; ++i) {
                int c = lane + i * 64;
                const float* ep = ET + (size_t)c * 64;
                float dot = 0.f;
#pragma unroll
                for (int j = 0; j < 64; ++j) dot = fmaf(xf[j * 132 + posl], ep[j], dot);
                float sc = fmaf(-2.f, dot, e2s[c]);
                unsigned long long kq = ((unsigned long long)mono_f32(sc) << 32) | (unsigned)c;
                if (kq < bkey) bkey = kq;
            }
#pragma unroll
            for (int off = 32; off > 0; off >>= 1) {
                unsigned long long o = __shfl_down(bkey, off);
                if (o < bkey) bkey = o;
            }
            if (lane == 0) s_kk[posl] = (int)(bkey & 0x3FFull);
        }
    }
    __syncthreads();

    // epilogue: 512 thr = 32 pos-groups (4 pos) x 16 chan-groups (4 chan)
    {
        int pg = tid & 31;
        int ch4 = tid >> 5;       // 0..15
        int c0 = ch4 * 4;
        int p4 = pg * 4;
        int np = n0 + p4;

        int kk[4];
#pragma unroll
        for (int p = 0; p < 4; ++p) kk[p] = s_kk[p4 + p];

        float4 xv4[4];
#pragma unroll
        for (int c = 0; c < 4; ++c) xv4[c] = *(float4*)&xf[(c0 + c) * 132 + p4];

        float4 eg[4];
#pragma unroll
        for (int p = 0; p < 4; ++p) eg[p] = *(const float4*)(ET + (size_t)kk[p] * 64 + c0);

        float* qb = out + OFF_Q + (size_t)b * 262144 + r0;
        float sq = 0.f;
#pragma unroll
        for (int c = 0; c < 4; ++c) {
            float4 qv = make_float4(((const float*)&eg[0])[c], ((const float*)&eg[1])[c],
                                    ((const float*)&eg[2])[c], ((const float*)&eg[3])[c]);
            *(float4*)(qb + (c0 + c) * 4096 + p4) = qv;
            float d0 = qv.x - ((const float*)&xv4[c])[0];
            float d1 = qv.y - ((const float*)&xv4[c])[1];
            float d2 = qv.z - ((const float*)&xv4[c])[2];
            float d3 = qv.w - ((const float*)&xv4[c])[3];
            sq = fmaf(d0, d0, sq); sq = fmaf(d1, d1, sq);
            sq = fmaf(d2, d2, sq); sq = fmaf(d3, d3, sq);
        }

        if (xT) {
#pragma unroll
            for (int p = 0; p < 4; ++p) {
                float4 tv = make_float4(((const float*)&xv4[0])[p], ((const float*)&xv4[1])[p],
                                        ((const float*)&xv4[2])[p], ((const float*)&xv4[3])[p]);
                *(float4*)(xT + (size_t)(np + p) * 64 + c0) = tv;
            }
        }

        if (ch4 == 0) {
#pragma unroll
            for (int p = 0; p < 4; ++p) out[OFF_IDX + np + p] = (float)kk[p];
            *(int4*)(idxi + np) = make_int4(kk[0], kk[1], kk[2], kk[3]);
#pragma unroll
            for (int p = 0; p < 4; ++p) atomicAdd(&hist[kk[p]], 1);
        }

#pragma unroll
        for (int off = 32; off > 0; off >>= 1) sq += __shfl_down(sq, off);
        if (lane == 0) atomicAdd(loss, sq);
    }
}

// One block: exclusive scan of hist + EMA stage1.
__global__ void __launch_bounds__(1024) scan_kernel(
    const int* __restrict__ hist, const float* __restrict__ cluster_size,
    const float* __restrict__ loss, float* __restrict__ out,
    float* __restrict__ cs_ws, int* __restrict__ cursor) {
    int t = threadIdx.x;
    __shared__ int sc[1024];
    __shared__ float fred[1024];
    int cnt = hist[t];
    sc[t] = cnt;
    __syncthreads();
    for (int off = 1; off < 1024; off <<= 1) {
        int v = (t >= off) ? sc[t - off] : 0;
        __syncthreads();
        sc[t] += v;
        __syncthreads();
    }
    cursor[t] = sc[t] - cnt;

    float ncs = cluster_size[t] * DECAYF + OMDF * (float)cnt;
    fred[t] = ncs;
    __syncthreads();
    for (int s = 512; s > 0; s >>= 1) {
        if (t < s) fred[t] += fred[t + s];
        __syncthreads();
    }
    float nsum = fred[0];
    out[OFF_NCS + t] = ncs;
    cs_ws[t] = (ncs + EPSF) / (nsum + 1024.f * EPSF) * nsum;
    if (t == 0) out[OFF_LOSS] = CCOST * loss[0] / (float)NELEM;
}

// R27: block-aggregated scatter (Guideline 12). LDS hist+rank, one global
// atomic per distinct k per block, conflict-free perm writes.
__global__ void __launch_bounds__(256) scatter_kernel(
    const int* __restrict__ idxi, int* __restrict__ cursor,
    unsigned* __restrict__ perm) {
    __shared__ int lhist[1024];
    __shared__ int lbase[1024];
    int tid = threadIdx.x;
#pragma unroll
    for (int i = 0; i < 4; ++i) lhist[i * 256 + tid] = 0;
    __syncthreads();
    int n = blockIdx.x * 256 + tid;
    int k = idxi[n];
    int rank = atomicAdd(&lhist[k], 1);
    __syncthreads();
#pragma unroll
    for (int i = 0; i < 4; ++i) {
        int kk = i * 256 + tid;
        int c = lhist[kk];
        if (c > 0) lbase[kk] = atomicAdd(&cursor[kk], c);
    }
    __syncthreads();
    perm[lbase[k] + rank] = ((unsigned)k << 17) | (unsigned)n;  // k:10b, n:17b
}

// Balanced segmented reduction over sorted perm; wave = 32 entries.
__global__ void __launch_bounds__(256) dw_accum_kernel(
    const float* __restrict__ in, const float* __restrict__ xT,
    const unsigned* __restrict__ perm, float* __restrict__ dwT) {
    int t = threadIdx.x;
    int c = t & 63;
    int wv = t >> 6;
    int base = (blockIdx.x * 4 + wv) * 32;  // 2048 waves x 32 = 65536

    __shared__ unsigned spm[4][32];
    if (c < 32) spm[wv][c] = perm[base + c];
    __syncthreads();

    float acc = 0.f;
    unsigned cur = spm[wv][0] >> 17;
#pragma unroll 4
    for (int i = 0; i < 32; ++i) {
        unsigned e = spm[wv][i];  // broadcast
        unsigned k = e >> 17;
        unsigned n = e & 0x1FFFFu;
        if (k != cur) {  // wave-uniform
            atomicAdd(&dwT[cur * 64 + c], acc);
            acc = 0.f;
            cur = k;
        }
        if (xT) {
            acc += xT[(size_t)n * 64 + c];  // 256B contiguous per wave
        } else {
            acc += in[(size_t)(n >> 12) * 262144 + c * 4096 + (n & 4095)];
        }
    }
    atomicAdd(&dwT[cur * 64 + c], acc);
}

__global__ void __launch_bounds__(256) ema2_kernel(
    const float* __restrict__ embed_avg, const float* __restrict__ dwT,
    const float* __restrict__ cs_ws, float* __restrict__ out) {
    int i = blockIdx.x * 256 + threadIdx.x;  // i = c*K + k
    int k = i & (K - 1);
    int c = i >> 10;
    float avg = embed_avg[i] * DECAYF + OMDF * dwT[k * 64 + c];
    out[OFF_AVG + i] = avg;
    out[OFF_EMB + i] = avg / cs_ws[k];
}

extern "C" void kernel_launch(void* const* d_in, const int* in_sizes, int n_in,
                              void* d_out, int out_size, void* d_ws, size_t ws_size,
                              hipStream_t stream) {
    const float* in = (const float*)d_in[0];
    const float* E = (const float*)d_in[1];
    const float* cluster_size = (const float*)d_in[2];
    const float* embed_avg = (const float*)d_in[3];
    float* out = (float*)d_out;
    float* ws = (float*)d_ws;

    float* loss = ws;
    float* e2 = ws + 64;
    float* cs = ws + 1088;
    int* cursor = (int*)(ws + 2112);   // 1024
    int* hist = (int*)(ws + 3136);     // 1024
    int* idxi = (int*)(ws + 4224);     // 65536
    unsigned* perm = (unsigned*)(ws + 69760);  // 65536
    _Float16* Ef = (_Float16*)(ws + 135296);   // 131072 halves
    float* dwT = ws + 266368;          // 65536 ([K][64])
    float* ET = ws + 331904;           // 65536 ([K][64])
    float* xT = (ws_size >= (397440ull + 4194304ull) * 4ull) ? (ws + 397440) : nullptr;

    prep_kernel<<<K / 64, 256, 0, stream>>>(E, ET, e2, Ef, hist, loss, dwT);
    score_kernel<<<512, 512, 0, stream>>>(in, Ef, ET, e2, out, idxi, xT, loss, hist);
    scan_kernel<<<1, 1024, 0, stream>>>(hist, cluster_size, loss, out, cs, cursor);
    scatter_kernel<<<NPOS / 256, 256, 0, stream>>>(idxi, cursor, perm);
    dw_accum_kernel<<<512, 256, 0, stream>>>(in, xT, perm, dwT);
    ema2_kernel<<<D * K / 256, 256, 0, stream>>>(embed_avg, dwT, cs, out);
}

// Round 16
// 187.507 us; speedup vs baseline: 1.6959x; 1.0418x over previous
//
#include <hip/hip_runtime.h>
#include <float.h>

// VQ-VAE EMA vector quantizer, MI355X (gfx950).
// inputs:  [16,64,64,64] f32 (b,c,h,w) -> N=65536 positions, d=64
// embedding: [64,1024] f32 (d,K)
//
// Lessons: R7  — cooperative grid.sync ~30-40us each; separate launches win.
//          R10 — cross-block ticket + device fences = 9x regression. Never.
//          R13 — bucket skew: per-code WORK ASSIGNMENT = serial straggler.
//          R24 — bucket skew pt.2: per-code ATOMIC ACCUMULATION dies too.
//                Balanced sorted-perm dw only.
//          R21/R22 — MFMA f16 hi/lo + exact-f32 fixup; frag-linear Ef16.
//          R23/R26 — fused score+finalize: score 99, total 226-230.
//          R27/R29 — aggregated scatter + coalesced Ef16 build: 193-195.
//                PROVEN. Score: MfmaUtil 20%, VALU 22%, Occ 27%, VGPR 60.
//          R28 — 1024-thr occupancy push FAILED via VGPR CAP (40) -> B-frag
//                scratch spill (FETCH 234MB). Never tested occupancy itself.
// R30 (this): occupancy retry WITHOUT the register confound. Keep 512-thr
//      blocks + launch_bounds(512,2) (same compile, 60 VGPR), halve tile
//      to 64 pos -> grid 1024 -> 4 blocks/CU. LDS ~28KB (4x28=112<=160),
//      VGPR 60 -> 8 waves/SIMD -> 32 waves/CU (2x R27). Wave = 64pos x
//      128codes (grt=wc*2+rt, R28's partition at R27's budget). Total MFMA
//      count and per-(pos,code) math identical. Ef16 L2 re-reads double
//      (256MB ~ 7us aggregate, hidden). Fixup/epilogue remapped, same
//      arithmetic. Predict: score ~65-75 (Occ 45-55%, VGPR 60), total
//      ~165-175. If score >=95: stall is serial-phase -> abandon occupancy
//      lever, try K=32 MFMA shape next.

#define K 1024
#define D 64
#define NPOS 65536
#define NELEM 4194304
#define DECAYF 0.99f
#define OMDF 0.01f
#define EPSF 1e-5f
#define CCOST 0.25f
#define DELTA 0.004f

#define OFF_Q 0
#define OFF_LOSS 4194304
#define OFF_IDX 4194305
#define OFF_EMB 4259841
#define OFF_NCS 4325377
#define OFF_AVG 4326401

typedef _Float16 half4 __attribute__((ext_vector_type(4)));
typedef _Float16 half8 __attribute__((ext_vector_type(8)));
typedef float f32x4 __attribute__((ext_vector_type(4)));

// ws float layout:
// [0] loss | [64..1088) e2 | [1088..2112) cs | [2112..3136) cursor(int)
// [3136..4160) hist(int) | [4224..69760) idxi(int)
// [69760..135296) perm(u32)
// [135296..266368) Ef16 region (131072 halves = 256KB)
// [266368..331904) dwT[K][64] | [331904..397440) ET[K][64]
// [397440..) xT[n][64] (optional, 16 MB)
//
// Ef16 frag-linear layout (halves): block (kt,grt,s) of 512 halves at
//   ((kt*16+grt)*4+s)*512, lane entry = lane*8 + half*4 + j
//   (Ah 4 halves | Al 4 halves = one 16B lane chunk, coalesced).

// Tile-transpose E -> ET[K][64], fused e2, Ef16 fragment build (coalesced);
// init hist/loss/dwT (no memsets).
__global__ void __launch_bounds__(256) prep_kernel(
    const float* __restrict__ E, float* __restrict__ ET, float* __restrict__ e2,
    _Float16* __restrict__ Ef, int* __restrict__ hist,
    float* __restrict__ loss, float* __restrict__ dwT) {
    __shared__ float tile[64][65];
    __shared__ float part[4][64];
    int tid = threadIdx.x;
    int gid = blockIdx.x * 256 + tid;  // 0..4095
#pragma unroll
    for (int i = 0; i < 16; ++i) dwT[i * 4096 + gid] = 0.f;
    if (gid < K) hist[gid] = 0;
    if (gid == 0) *loss = 0.f;

    int k0 = blockIdx.x * 64;
    int kl = tid & 63;
    int cg_ = tid >> 6;  // 0..3
#pragma unroll
    for (int cc = 0; cc < 16; ++cc) {
        int c = cc * 4 + cg_;
        tile[c][kl] = E[c * K + k0 + kl];  // coalesced
    }
    __syncthreads();
    float s = 0.f;
#pragma unroll
    for (int i = 0; i < 16; ++i) {
        float v = tile[cg_ * 16 + i][kl];
        s = fmaf(v, v, s);
    }
    part[cg_][kl] = s;
#pragma unroll
    for (int i = 0; i < 16; ++i) {
        int w = i * 256 + tid;
        int k = w >> 6, c = w & 63;
        ET[(size_t)(k0 + k) * 64 + c] = tile[c][k];
    }
    // Ef16 fragment build: one coalesced 16B store per iteration.
    {
        int lane_ = tid & 63;
        int s_ = tid >> 6;        // 0..3
        int g_ = lane_ >> 4;      // 0..3
        int l15 = lane_ & 15;
        int kt = k0 >> 8;
#pragma unroll
        for (int ch = 0; ch < 4; ++ch) {
            int code_local = ch * 16 + l15;
            int code = k0 + code_local;
            int grt = (code >> 4) & 15;
            half8 hl;
#pragma unroll
            for (int j = 0; j < 4; ++j) {
                float v = tile[s_ * 16 + g_ * 4 + j][code_local];
                _Float16 h = (_Float16)v;
                hl[j] = h;
                hl[4 + j] = (_Float16)(v - (float)h);
            }
            size_t off = (size_t)((kt * 16 + grt) * 4 + s_) * 512 + (size_t)lane_ * 8;
            *(half8*)(Ef + off) = hl;
        }
    }
    __syncthreads();
    if (tid < 64) e2[k0 + tid] = part[0][tid] + part[1][tid] + part[2][tid] + part[3][tid];
}

__device__ __forceinline__ unsigned mono_f32(float s) {
    unsigned u = __float_as_uint(s);
    return (u & 0x80000000u) ? ~u : (u | 0x80000000u);
}

// R30 fused score+finalize: 512 thr = 8 waves, wave = 64 pos x 128 codes
// (wc = w in 0..7; grt = wc*2 + rt, rt 0..1). Block = 64 pos x 1024 codes;
// grid 1024 -> 4 blocks/CU -> 32 waves/CU. A-frags from L2-resident Ef16;
// x staged once in LDS (f32, reused). MFMA kt-loop barrier-free.
__global__ void __launch_bounds__(512, 2) score_kernel(
    const float* __restrict__ in, const _Float16* __restrict__ Ef,
    const float* __restrict__ ET, const float* __restrict__ e2,
    float* __restrict__ out, int* __restrict__ idxi, float* __restrict__ xT,
    float* __restrict__ loss, int* __restrict__ hist) {
    __shared__ __align__(16) float xf[64 * 68];   // [chan][pos 64] padded, 17.4KB
    __shared__ float e2s[1024];
    __shared__ float mgb[64][8];
    __shared__ int   mgi[64][8];
    __shared__ float mgs[64][8];
    __shared__ int s_kk[64];
    __shared__ int s_fl[64];
    __shared__ int s_nf;

    int tid = threadIdx.x;
    int lane = tid & 63;
    int w = tid >> 6;  // 0..7
    int wc = w;        // code-eighth 0..7
    int g = lane >> 4; // 0..3
    int c16 = lane & 15;

    int n0 = blockIdx.x * 64;
    int b = n0 >> 12;
    int r0 = n0 & 4095;

    if (tid == 0) s_nf = 0;

    // stage x f32 tile [64 chan][64 pos]
#pragma unroll
    for (int it = 0; it < 2; ++it) {
        int idx = it * 512 + tid;   // 0..1023
        int c = idx >> 4;
        int q = idx & 15;
        float4 v = *(const float4*)(in + (size_t)b * 262144 + c * 4096 + r0 + q * 4);
        *(float4*)(&xf[c * 68 + q * 4]) = v;
    }
    e2s[tid] = e2[tid];
    e2s[512 + tid] = e2[512 + tid];
    __syncthreads();

    // persistent x fragments (B operand): k=(lane>>4)*4+j+s*16, col=pos
    half4 Bh[4][4], Bl[4][4];   // [pt][s]
#pragma unroll
    for (int pt = 0; pt < 4; ++pt) {
        int p = pt * 16 + c16;
#pragma unroll
        for (int s = 0; s < 4; ++s) {
            half4 hh, ll;
#pragma unroll
            for (int j = 0; j < 4; ++j) {
                float v = xf[(g * 4 + j + s * 16) * 68 + p];
                _Float16 h = (_Float16)v;
                hh[j] = h;
                ll[j] = (_Float16)(v - (float)h);
            }
            Bh[pt][s] = hh; Bl[pt][s] = ll;
        }
    }

    float best[4], sec[4]; int bk[4];
#pragma unroll
    for (int pt = 0; pt < 4; ++pt) { best[pt] = FLT_MAX; sec[pt] = FLT_MAX; bk[pt] = 0; }

    for (int kt = 0; kt < 4; ++kt) {
#pragma unroll
        for (int rt = 0; rt < 2; ++rt) {
            int grt = wc * 2 + rt;
            f32x4 acc[4];
#pragma unroll
            for (int pt = 0; pt < 4; ++pt) acc[pt] = {0.f, 0.f, 0.f, 0.f};
#pragma unroll
            for (int s = 0; s < 4; ++s) {
                const _Float16* eb = Ef + (size_t)((kt * 16 + grt) * 4 + s) * 512 + lane * 8;
                half4 Ah = *(const half4*)eb;
                half4 Al = *(const half4*)(eb + 4);
#pragma unroll
                for (int pt = 0; pt < 4; ++pt)
                    acc[pt] = __builtin_amdgcn_mfma_f32_16x16x16f16(Ah, Bh[pt][s], acc[pt], 0, 0, 0);
#pragma unroll
                for (int pt = 0; pt < 4; ++pt)
                    acc[pt] = __builtin_amdgcn_mfma_f32_16x16x16f16(Ah, Bl[pt][s], acc[pt], 0, 0, 0);
#pragma unroll
                for (int pt = 0; pt < 4; ++pt)
                    acc[pt] = __builtin_amdgcn_mfma_f32_16x16x16f16(Al, Bh[pt][s], acc[pt], 0, 0, 0);
            }
            int cb = kt * 256 + grt * 16 + g * 4;
#pragma unroll
            for (int r = 0; r < 4; ++r) {
                float ev2 = e2s[cb + r];
                int code = cb + r;
#pragma unroll
                for (int pt = 0; pt < 4; ++pt) {
                    float sc = fmaf(-2.f, acc[pt][r], ev2);
                    if (sc < best[pt]) { sec[pt] = best[pt]; best[pt] = sc; bk[pt] = code; }
                    else sec[pt] = fminf(sec[pt], sc);
                }
            }
        }
    }

    // merge the 4 lane-groups (disjoint code ranges, same pos col)
#pragma unroll
    for (int pt = 0; pt < 4; ++pt) {
#pragma unroll
        for (int m = 16; m <= 32; m <<= 1) {
            float ob = __shfl_xor(best[pt], m);
            int obk = __shfl_xor(bk[pt], m);
            float os = __shfl_xor(sec[pt], m);
            bool take = (ob < best[pt]) || (ob == best[pt] && obk < bk[pt]);
            float ns = take ? fminf(os, best[pt]) : fminf(sec[pt], ob);
            best[pt] = take ? ob : best[pt];
            bk[pt] = take ? obk : bk[pt];
            sec[pt] = ns;
        }
        if (lane < 16) {
            int posl = pt * 16 + lane;
            mgb[posl][wc] = best[pt]; mgi[posl][wc] = bk[pt]; mgs[posl][wc] = sec[pt];
        }
    }
    __syncthreads();
    if (tid < 64) {
        float bb = mgb[tid][0]; int kw = mgi[tid][0]; float ss = mgs[tid][0];
#pragma unroll
        for (int i = 1; i < 8; ++i) {
            float ob = mgb[tid][i]; int ok = mgi[tid][i]; float os = mgs[tid][i];
            bool take = (ob < bb) || (ob == bb && ok < kw);
            ss = take ? fminf(os, bb) : fminf(ss, ob);
            bb = take ? ob : bb;
            kw = take ? ok : kw;
        }
        s_kk[tid] = kw;
        if ((ss - bb) < DELTA) {
            int sl = atomicAdd(&s_nf, 1);
            s_fl[sl] = tid;
        }
    }
    __syncthreads();

    // fixup: exact f32 argmin for flagged positions; one wave per position.
    // Sequential-fmaf dot — IDENTICAL rounding to R22's fixup (proven).
    int nf = s_nf;
    for (int f0 = 0; f0 < nf; f0 += 8) {
        int f = f0 + w;
        if (f < nf) {
            int posl = s_fl[f];
            unsigned long long bkey = ~0ull;
            for (int i = 0; i < 16; ++i) {
                int c = lane + i * 64;
                const float* ep = ET + (size_t)c * 64;
                float dot = 0.f;
#pragma unroll
                for (int j = 0; j < 64; ++j) dot = fmaf(xf[j * 68 + posl], ep[j], dot);
                float sc = fmaf(-2.f, dot, e2s[c]);
                unsigned long long kq = ((unsigned long long)mono_f32(sc) << 32) | (unsigned)c;
                if (kq < bkey) bkey = kq;
            }
#pragma unroll
            for (int off = 32; off > 0; off >>= 1) {
                unsigned long long o = __shfl_down(bkey, off);
                if (o < bkey) bkey = o;
            }
            if (lane == 0) s_kk[posl] = (int)(bkey & 0x3FFull);
        }
    }
    __syncthreads();

    // epilogue: tid<256 = 16 pos-groups (4 pos) x 16 chan-groups (4 chan)
    if (tid < 256) {
        int pg = tid & 15;
        int ch4 = tid >> 4;       // 0..15
        int c0 = ch4 * 4;
        int p4 = pg * 4;
        int np = n0 + p4;

        int kk[4];
#pragma unroll
        for (int p = 0; p < 4; ++p) kk[p] = s_kk[p4 + p];

        float4 xv4[4];
#pragma unroll
        for (int c = 0; c < 4; ++c) xv4[c] = *(float4*)&xf[(c0 + c) * 68 + p4];

        float4 eg[4];
#pragma unroll
        for (int p = 0; p < 4; ++p) eg[p] = *(const float4*)(ET + (size_t)kk[p] * 64 + c0);

        float* qb = out + OFF_Q + (size_t)b * 262144 + r0;
        float sq = 0.f;
#pragma unroll
        for (int c = 0; c < 4; ++c) {
            float4 qv = make_float4(((const float*)&eg[0])[c], ((const float*)&eg[1])[c],
                                    ((const float*)&eg[2])[c], ((const float*)&eg[3])[c]);
            *(float4*)(qb + (c0 + c) * 4096 + p4) = qv;
            float d0 = qv.x - ((const float*)&xv4[c])[0];
            float d1 = qv.y - ((const float*)&xv4[c])[1];
            float d2 = qv.z - ((const float*)&xv4[c])[2];
            float d3 = qv.w - ((const float*)&xv4[c])[3];
            sq = fmaf(d0, d0, sq); sq = fmaf(d1, d1, sq);
            sq = fmaf(d2, d2, sq); sq = fmaf(d3, d3, sq);
        }

        if (xT) {
#pragma unroll
            for (int p = 0; p < 4; ++p) {
                float4 tv = make_float4(((const float*)&xv4[0])[p], ((const float*)&xv4[1])[p],
                                        ((const float*)&xv4[2])[p], ((const float*)&xv4[3])[p]);
                *(float4*)(xT + (size_t)(np + p) * 64 + c0) = tv;
            }
        }

        if (ch4 == 0) {
#pragma unroll
            for (int p = 0; p < 4; ++p) out[OFF_IDX + np + p] = (float)kk[p];
            *(int4*)(idxi + np) = make_int4(kk[0], kk[1], kk[2], kk[3]);
#pragma unroll
            for (int p = 0; p < 4; ++p) atomicAdd(&hist[kk[p]], 1);
        }

#pragma unroll
        for (int off = 32; off > 0; off >>= 1) sq += __shfl_down(sq, off);
        if ((tid & 63) == 0) atomicAdd(loss, sq);
    }
}

// One block: exclusive scan of hist + EMA stage1.
__global__ void __launch_bounds__(1024) scan_kernel(
    const int* __restrict__ hist, const float* __restrict__ cluster_size,
    const float* __restrict__ loss, float* __restrict__ out,
    float* __restrict__ cs_ws, int* __restrict__ cursor) {
    int t = threadIdx.x;
    __shared__ int sc[1024];
    __shared__ float fred[1024];
    int cnt = hist[t];
    sc[t] = cnt;
    __syncthreads();
    for (int off = 1; off < 1024; off <<= 1) {
        int v = (t >= off) ? sc[t - off] : 0;
        __syncthreads();
        sc[t] += v;
        __syncthreads();
    }
    cursor[t] = sc[t] - cnt;

    float ncs = cluster_size[t] * DECAYF + OMDF * (float)cnt;
    fred[t] = ncs;
    __syncthreads();
    for (int s = 512; s > 0; s >>= 1) {
        if (t < s) fred[t] += fred[t + s];
        __syncthreads();
    }
    float nsum = fred[0];
    out[OFF_NCS + t] = ncs;
    cs_ws[t] = (ncs + EPSF) / (nsum + 1024.f * EPSF) * nsum;
    if (t == 0) out[OFF_LOSS] = CCOST * loss[0] / (float)NELEM;
}

// R27: block-aggregated scatter (Guideline 12). LDS hist+rank, one global
// atomic per distinct k per block, conflict-free perm writes.
__global__ void __launch_bounds__(256) scatter_kernel(
    const int* __restrict__ idxi, int* __restrict__ cursor,
    unsigned* __restrict__ perm) {
    __shared__ int lhist[1024];
    __shared__ int lbase[1024];
    int tid = threadIdx.x;
#pragma unroll
    for (int i = 0; i < 4; ++i) lhist[i * 256 + tid] = 0;
    __syncthreads();
    int n = blockIdx.x * 256 + tid;
    int k = idxi[n];
    int rank = atomicAdd(&lhist[k], 1);
    __syncthreads();
#pragma unroll
    for (int i = 0; i < 4; ++i) {
        int kk = i * 256 + tid;
        int c = lhist[kk];
        if (c > 0) lbase[kk] = atomicAdd(&cursor[kk], c);
    }
    __syncthreads();
    perm[lbase[k] + rank] = ((unsigned)k << 17) | (unsigned)n;  // k:10b, n:17b
}

// Balanced segmented reduction over sorted perm; wave = 32 entries.
__global__ void __launch_bounds__(256) dw_accum_kernel(
    const float* __restrict__ in, const float* __restrict__ xT,
    const unsigned* __restrict__ perm, float* __restrict__ dwT) {
    int t = threadIdx.x;
    int c = t & 63;
    int wv = t >> 6;
    int base = (blockIdx.x * 4 + wv) * 32;  // 2048 waves x 32 = 65536

    __shared__ unsigned spm[4][32];
    if (c < 32) spm[wv][c] = perm[base + c];
    __syncthreads();

    float acc = 0.f;
    unsigned cur = spm[wv][0] >> 17;
#pragma unroll 4
    for (int i = 0; i < 32; ++i) {
        unsigned e = spm[wv][i];  // broadcast
        unsigned k = e >> 17;
        unsigned n = e & 0x1FFFFu;
        if (k != cur) {  // wave-uniform
            atomicAdd(&dwT[cur * 64 + c], acc);
            acc = 0.f;
            cur = k;
        }
        if (xT) {
            acc += xT[(size_t)n * 64 + c];  // 256B contiguous per wave
        } else {
            acc += in[(size_t)(n >> 12) * 262144 + c * 4096 + (n & 4095)];
        }
    }
    atomicAdd(&dwT[cur * 64 + c], acc);
}

__global__ void __launch_bounds__(256) ema2_kernel(
    const float* __restrict__ embed_avg, const float* __restrict__ dwT,
    const float* __restrict__ cs_ws, float* __restrict__ out) {
    int i = blockIdx.x * 256 + threadIdx.x;  // i = c*K + k
    int k = i & (K - 1);
    int c = i >> 10;
    float avg = embed_avg[i] * DECAYF + OMDF * dwT[k * 64 + c];
    out[OFF_AVG + i] = avg;
    out[OFF_EMB + i] = avg / cs_ws[k];
}

extern "C" void kernel_launch(void* const* d_in, const int* in_sizes, int n_in,
                              void* d_out, int out_size, void* d_ws, size_t ws_size,
                              hipStream_t stream) {
    const float* in = (const float*)d_in[0];
    const float* E = (const float*)d_in[1];
    const float* cluster_size = (const float*)d_in[2];
    const float* embed_avg = (const float*)d_in[3];
    float* out = (float*)d_out;
    float* ws = (float*)d_ws;

    float* loss = ws;
    float* e2 = ws + 64;
    float* cs = ws + 1088;
    int* cursor = (int*)(ws + 2112);   // 1024
    int* hist = (int*)(ws + 3136);     // 1024
    int* idxi = (int*)(ws + 4224);     // 65536
    unsigned* perm = (unsigned*)(ws + 69760);  // 65536
    _Float16* Ef = (_Float16*)(ws + 135296);   // 131072 halves
    float* dwT = ws + 266368;          // 65536 ([K][64])
    float* ET = ws + 331904;           // 65536 ([K][64])
    float* xT = (ws_size >= (397440ull + 4194304ull) * 4ull) ? (ws + 397440) : nullptr;

    prep_kernel<<<K / 64, 256, 0, stream>>>(E, ET, e2, Ef, hist, loss, dwT);
    score_kernel<<<1024, 512, 0, stream>>>(in, Ef, ET, e2, out, idxi, xT, loss, hist);
    scan_kernel<<<1, 1024, 0, stream>>>(hist, cluster_size, loss, out, cs, cursor);
    scatter_kernel<<<NPOS / 256, 256, 0, stream>>>(idxi, cursor, perm);
    dw_accum_kernel<<<512, 256, 0, stream>>>(in, xT, perm, dwT);
    ema2_kernel<<<D * K / 256, 256, 0, stream>>>(embed_avg, dwT, cs, out);
}

// Round 17
// 172.160 us; speedup vs baseline: 1.8471x; 1.0891x over previous
//
#include <hip/hip_runtime.h>
#include <float.h>

// VQ-VAE EMA vector quantizer, MI355X (gfx950).
// inputs:  [16,64,64,64] f32 (b,c,h,w) -> N=65536 positions, d=64
// embedding: [64,1024] f32 (d,K)
//
// Lessons: R7  — cooperative grid.sync ~30-40us each; separate launches win.
//          R10 — cross-block ticket + device fences = 9x regression. Never.
//          R13 — bucket skew: per-code WORK ASSIGNMENT = serial straggler.
//          R24 — bucket skew pt.2: per-code ATOMIC ACCUMULATION dies
//                (~40cyc same-address f32 RMW x hot-bucket ~25K = 100s of us).
//          R21/R22 — MFMA f16 hi/lo + exact-f32 fixup; frag-linear Ef16.
//          R23/R26 — fused score+finalize: score 99, total 226-230.
//          R27/R29 — aggregated scatter + coalesced Ef16: 193-195. PROVEN.
//          R28 — occupancy push via VGPR cap: spill disaster. 318.
//          R30 — occupancy push clean (64-pos tile, 2x waves): score 96.5
//                (UNCHANGED — stall is NOT TLP-recoverable), total 187.5
//                (best; tail shrank from smaller-grid overlap). Occupancy
//                lever DEAD for score.
// R31 (this): epilogue-atomic aggregation. Decomposition: kt-loop ~38us
//      (R8), epilogue ~60us in BOTH fused and standalone forms at ~7us
//      memory floor, concurrency-insensitive -> same-address atomic queue
//      on hist (hot code ~25K arrivals x ~4-40cyc = invisible-to-counters
//      serialization). Fix per Guideline 12: LDS hist per block -> 1
//      global atomic per DISTINCT code (<=64/block, hot-addr 25K->1024,
//      25x); loss -> 1 atomic/block via LDS. Integer hist exact; loss
//      reorder within tolerance. All else byte-identical to R30.
//      Predict: score ~70-85, total ~160-175. If score unchanged: atomics
//      exonerated -> K=32 MFMA next.

#define K 1024
#define D 64
#define NPOS 65536
#define NELEM 4194304
#define DECAYF 0.99f
#define OMDF 0.01f
#define EPSF 1e-5f
#define CCOST 0.25f
#define DELTA 0.004f

#define OFF_Q 0
#define OFF_LOSS 4194304
#define OFF_IDX 4194305
#define OFF_EMB 4259841
#define OFF_NCS 4325377
#define OFF_AVG 4326401

typedef _Float16 half4 __attribute__((ext_vector_type(4)));
typedef _Float16 half8 __attribute__((ext_vector_type(8)));
typedef float f32x4 __attribute__((ext_vector_type(4)));

// ws float layout:
// [0] loss | [64..1088) e2 | [1088..2112) cs | [2112..3136) cursor(int)
// [3136..4160) hist(int) | [4224..69760) idxi(int)
// [69760..135296) perm(u32)
// [135296..266368) Ef16 region (131072 halves = 256KB)
// [266368..331904) dwT[K][64] | [331904..397440) ET[K][64]
// [397440..) xT[n][64] (optional, 16 MB)
//
// Ef16 frag-linear layout (halves): block (kt,grt,s) of 512 halves at
//   ((kt*16+grt)*4+s)*512, lane entry = lane*8 + half*4 + j
//   (Ah 4 halves | Al 4 halves = one 16B lane chunk, coalesced).

// Tile-transpose E -> ET[K][64], fused e2, Ef16 fragment build (coalesced);
// init hist/loss/dwT (no memsets).
__global__ void __launch_bounds__(256) prep_kernel(
    const float* __restrict__ E, float* __restrict__ ET, float* __restrict__ e2,
    _Float16* __restrict__ Ef, int* __restrict__ hist,
    float* __restrict__ loss, float* __restrict__ dwT) {
    __shared__ float tile[64][65];
    __shared__ float part[4][64];
    int tid = threadIdx.x;
    int gid = blockIdx.x * 256 + tid;  // 0..4095
#pragma unroll
    for (int i = 0; i < 16; ++i) dwT[i * 4096 + gid] = 0.f;
    if (gid < K) hist[gid] = 0;
    if (gid == 0) *loss = 0.f;

    int k0 = blockIdx.x * 64;
    int kl = tid & 63;
    int cg_ = tid >> 6;  // 0..3
#pragma unroll
    for (int cc = 0; cc < 16; ++cc) {
        int c = cc * 4 + cg_;
        tile[c][kl] = E[c * K + k0 + kl];  // coalesced
    }
    __syncthreads();
    float s = 0.f;
#pragma unroll
    for (int i = 0; i < 16; ++i) {
        float v = tile[cg_ * 16 + i][kl];
        s = fmaf(v, v, s);
    }
    part[cg_][kl] = s;
#pragma unroll
    for (int i = 0; i < 16; ++i) {
        int w = i * 256 + tid;
        int k = w >> 6, c = w & 63;
        ET[(size_t)(k0 + k) * 64 + c] = tile[c][k];
    }
    // Ef16 fragment build: one coalesced 16B store per iteration.
    {
        int lane_ = tid & 63;
        int s_ = tid >> 6;        // 0..3
        int g_ = lane_ >> 4;      // 0..3
        int l15 = lane_ & 15;
        int kt = k0 >> 8;
#pragma unroll
        for (int ch = 0; ch < 4; ++ch) {
            int code_local = ch * 16 + l15;
            int code = k0 + code_local;
            int grt = (code >> 4) & 15;
            half8 hl;
#pragma unroll
            for (int j = 0; j < 4; ++j) {
                float v = tile[s_ * 16 + g_ * 4 + j][code_local];
                _Float16 h = (_Float16)v;
                hl[j] = h;
                hl[4 + j] = (_Float16)(v - (float)h);
            }
            size_t off = (size_t)((kt * 16 + grt) * 4 + s_) * 512 + (size_t)lane_ * 8;
            *(half8*)(Ef + off) = hl;
        }
    }
    __syncthreads();
    if (tid < 64) e2[k0 + tid] = part[0][tid] + part[1][tid] + part[2][tid] + part[3][tid];
}

__device__ __forceinline__ unsigned mono_f32(float s) {
    unsigned u = __float_as_uint(s);
    return (u & 0x80000000u) ? ~u : (u | 0x80000000u);
}

// R31 fused score+finalize: 512 thr = 8 waves, wave = 64 pos x 128 codes
// (wc = w in 0..7; grt = wc*2 + rt). Block = 64 pos x 1024 codes; grid 1024.
// Epilogue atomics BLOCK-AGGREGATED (hist via LDS, loss via LDS).
__global__ void __launch_bounds__(512, 2) score_kernel(
    const float* __restrict__ in, const _Float16* __restrict__ Ef,
    const float* __restrict__ ET, const float* __restrict__ e2,
    float* __restrict__ out, int* __restrict__ idxi, float* __restrict__ xT,
    float* __restrict__ loss, int* __restrict__ hist) {
    __shared__ __align__(16) float xf[64 * 68];   // [chan][pos 64] padded, 17.4KB
    __shared__ float e2s[1024];
    __shared__ float mgb[64][8];
    __shared__ int   mgi[64][8];
    __shared__ float mgs[64][8];
    __shared__ int s_kk[64];
    __shared__ int s_fl[64];
    __shared__ int s_nf;
    __shared__ int lhist[1024];
    __shared__ float lloss[4];

    int tid = threadIdx.x;
    int lane = tid & 63;
    int w = tid >> 6;  // 0..7
    int wc = w;        // code-eighth 0..7
    int g = lane >> 4; // 0..3
    int c16 = lane & 15;

    int n0 = blockIdx.x * 64;
    int b = n0 >> 12;
    int r0 = n0 & 4095;

    if (tid == 0) s_nf = 0;
    lhist[tid] = 0;
    lhist[512 + tid] = 0;

    // stage x f32 tile [64 chan][64 pos]
#pragma unroll
    for (int it = 0; it < 2; ++it) {
        int idx = it * 512 + tid;   // 0..1023
        int c = idx >> 4;
        int q = idx & 15;
        float4 v = *(const float4*)(in + (size_t)b * 262144 + c * 4096 + r0 + q * 4);
        *(float4*)(&xf[c * 68 + q * 4]) = v;
    }
    e2s[tid] = e2[tid];
    e2s[512 + tid] = e2[512 + tid];
    __syncthreads();

    // persistent x fragments (B operand): k=(lane>>4)*4+j+s*16, col=pos
    half4 Bh[4][4], Bl[4][4];   // [pt][s]
#pragma unroll
    for (int pt = 0; pt < 4; ++pt) {
        int p = pt * 16 + c16;
#pragma unroll
        for (int s = 0; s < 4; ++s) {
            half4 hh, ll;
#pragma unroll
            for (int j = 0; j < 4; ++j) {
                float v = xf[(g * 4 + j + s * 16) * 68 + p];
                _Float16 h = (_Float16)v;
                hh[j] = h;
                ll[j] = (_Float16)(v - (float)h);
            }
            Bh[pt][s] = hh; Bl[pt][s] = ll;
        }
    }

    float best[4], sec[4]; int bk[4];
#pragma unroll
    for (int pt = 0; pt < 4; ++pt) { best[pt] = FLT_MAX; sec[pt] = FLT_MAX; bk[pt] = 0; }

    for (int kt = 0; kt < 4; ++kt) {
#pragma unroll
        for (int rt = 0; rt < 2; ++rt) {
            int grt = wc * 2 + rt;
            f32x4 acc[4];
#pragma unroll
            for (int pt = 0; pt < 4; ++pt) acc[pt] = {0.f, 0.f, 0.f, 0.f};
#pragma unroll
            for (int s = 0; s < 4; ++s) {
                const _Float16* eb = Ef + (size_t)((kt * 16 + grt) * 4 + s) * 512 + lane * 8;
                half4 Ah = *(const half4*)eb;
                half4 Al = *(const half4*)(eb + 4);
#pragma unroll
                for (int pt = 0; pt < 4; ++pt)
                    acc[pt] = __builtin_amdgcn_mfma_f32_16x16x16f16(Ah, Bh[pt][s], acc[pt], 0, 0, 0);
#pragma unroll
                for (int pt = 0; pt < 4; ++pt)
                    acc[pt] = __builtin_amdgcn_mfma_f32_16x16x16f16(Ah, Bl[pt][s], acc[pt], 0, 0, 0);
#pragma unroll
                for (int pt = 0; pt < 4; ++pt)
                    acc[pt] = __builtin_amdgcn_mfma_f32_16x16x16f16(Al, Bh[pt][s], acc[pt], 0, 0, 0);
            }
            int cb = kt * 256 + grt * 16 + g * 4;
#pragma unroll
            for (int r = 0; r < 4; ++r) {
                float ev2 = e2s[cb + r];
                int code = cb + r;
#pragma unroll
                for (int pt = 0; pt < 4; ++pt) {
                    float sc = fmaf(-2.f, acc[pt][r], ev2);
                    if (sc < best[pt]) { sec[pt] = best[pt]; best[pt] = sc; bk[pt] = code; }
                    else sec[pt] = fminf(sec[pt], sc);
                }
            }
        }
    }

    // merge the 4 lane-groups (disjoint code ranges, same pos col)
#pragma unroll
    for (int pt = 0; pt < 4; ++pt) {
#pragma unroll
        for (int m = 16; m <= 32; m <<= 1) {
            float ob = __shfl_xor(best[pt], m);
            int obk = __shfl_xor(bk[pt], m);
            float os = __shfl_xor(sec[pt], m);
            bool take = (ob < best[pt]) || (ob == best[pt] && obk < bk[pt]);
            float ns = take ? fminf(os, best[pt]) : fminf(sec[pt], ob);
            best[pt] = take ? ob : best[pt];
            bk[pt] = take ? obk : bk[pt];
            sec[pt] = ns;
        }
        if (lane < 16) {
            int posl = pt * 16 + lane;
            mgb[posl][wc] = best[pt]; mgi[posl][wc] = bk[pt]; mgs[posl][wc] = sec[pt];
        }
    }
    __syncthreads();
    if (tid < 64) {
        float bb = mgb[tid][0]; int kw = mgi[tid][0]; float ss = mgs[tid][0];
#pragma unroll
        for (int i = 1; i < 8; ++i) {
            float ob = mgb[tid][i]; int ok = mgi[tid][i]; float os = mgs[tid][i];
            bool take = (ob < bb) || (ob == bb && ok < kw);
            ss = take ? fminf(os, bb) : fminf(ss, ob);
            bb = take ? ob : bb;
            kw = take ? ok : kw;
        }
        s_kk[tid] = kw;
        if ((ss - bb) < DELTA) {
            int sl = atomicAdd(&s_nf, 1);
            s_fl[sl] = tid;
        }
    }
    __syncthreads();

    // fixup: exact f32 argmin for flagged positions; one wave per position.
    // Sequential-fmaf dot — IDENTICAL rounding to R22's fixup (proven).
    int nf = s_nf;
    for (int f0 = 0; f0 < nf; f0 += 8) {
        int f = f0 + w;
        if (f < nf) {
            int posl = s_fl[f];
            unsigned long long bkey = ~0ull;
            for (int i = 0; i < 16; ++i) {
                int c = lane + i * 64;
                const float* ep = ET + (size_t)c * 64;
                float dot = 0.f;
#pragma unroll
                for (int j = 0; j < 64; ++j) dot = fmaf(xf[j * 68 + posl], ep[j], dot);
                float sc = fmaf(-2.f, dot, e2s[c]);
                unsigned long long kq = ((unsigned long long)mono_f32(sc) << 32) | (unsigned)c;
                if (kq < bkey) bkey = kq;
            }
#pragma unroll
            for (int off = 32; off > 0; off >>= 1) {
                unsigned long long o = __shfl_down(bkey, off);
                if (o < bkey) bkey = o;
            }
            if (lane == 0) s_kk[posl] = (int)(bkey & 0x3FFull);
        }
    }
    __syncthreads();

    // epilogue: tid<256 = 16 pos-groups (4 pos) x 16 chan-groups (4 chan)
    if (tid < 256) {
        int pg = tid & 15;
        int ch4 = tid >> 4;       // 0..15
        int c0 = ch4 * 4;
        int p4 = pg * 4;
        int np = n0 + p4;

        int kk[4];
#pragma unroll
        for (int p = 0; p < 4; ++p) kk[p] = s_kk[p4 + p];

        float4 xv4[4];
#pragma unroll
        for (int c = 0; c < 4; ++c) xv4[c] = *(float4*)&xf[(c0 + c) * 68 + p4];

        float4 eg[4];
#pragma unroll
        for (int p = 0; p < 4; ++p) eg[p] = *(const float4*)(ET + (size_t)kk[p] * 64 + c0);

        float* qb = out + OFF_Q + (size_t)b * 262144 + r0;
        float sq = 0.f;
#pragma unroll
        for (int c = 0; c < 4; ++c) {
            float4 qv = make_float4(((const float*)&eg[0])[c], ((const float*)&eg[1])[c],
                                    ((const float*)&eg[2])[c], ((const float*)&eg[3])[c]);
            *(float4*)(qb + (c0 + c) * 4096 + p4) = qv;
            float d0 = qv.x - ((const float*)&xv4[c])[0];
            float d1 = qv.y - ((const float*)&xv4[c])[1];
            float d2 = qv.z - ((const float*)&xv4[c])[2];
            float d3 = qv.w - ((const float*)&xv4[c])[3];
            sq = fmaf(d0, d0, sq); sq = fmaf(d1, d1, sq);
            sq = fmaf(d2, d2, sq); sq = fmaf(d3, d3, sq);
        }

        if (xT) {
#pragma unroll
            for (int p = 0; p < 4; ++p) {
                float4 tv = make_float4(((const float*)&xv4[0])[p], ((const float*)&xv4[1])[p],
                                        ((const float*)&xv4[2])[p], ((const float*)&xv4[3])[p]);
                *(float4*)(xT + (size_t)(np + p) * 64 + c0) = tv;
            }
        }

        if (ch4 == 0) {
#pragma unroll
            for (int p = 0; p < 4; ++p) out[OFF_IDX + np + p] = (float)kk[p];
            *(int4*)(idxi + np) = make_int4(kk[0], kk[1], kk[2], kk[3]);
            // block-local hist (Guideline 12): LDS, then 1 global atomic
            // per distinct code after the barrier below.
#pragma unroll
            for (int p = 0; p < 4; ++p) atomicAdd(&lhist[kk[p]], 1);
        }

#pragma unroll
        for (int off = 32; off > 0; off >>= 1) sq += __shfl_down(sq, off);
        if ((tid & 63) == 0) lloss[tid >> 6] = sq;
    }
    __syncthreads();

    // drain aggregated atomics: <=64 distinct codes/block, 1 loss atomic.
    {
        int c0n = lhist[tid];
        if (c0n) atomicAdd(&hist[tid], c0n);
        int c1n = lhist[512 + tid];
        if (c1n) atomicAdd(&hist[512 + tid], c1n);
        if (tid == 0) atomicAdd(loss, lloss[0] + lloss[1] + lloss[2] + lloss[3]);
    }
}

// One block: exclusive scan of hist + EMA stage1.
__global__ void __launch_bounds__(1024) scan_kernel(
    const int* __restrict__ hist, const float* __restrict__ cluster_size,
    const float* __restrict__ loss, float* __restrict__ out,
    float* __restrict__ cs_ws, int* __restrict__ cursor) {
    int t = threadIdx.x;
    __shared__ int sc[1024];
    __shared__ float fred[1024];
    int cnt = hist[t];
    sc[t] = cnt;
    __syncthreads();
    for (int off = 1; off < 1024; off <<= 1) {
        int v = (t >= off) ? sc[t - off] : 0;
        __syncthreads();
        sc[t] += v;
        __syncthreads();
    }
    cursor[t] = sc[t] - cnt;

    float ncs = cluster_size[t] * DECAYF + OMDF * (float)cnt;
    fred[t] = ncs;
    __syncthreads();
    for (int s = 512; s > 0; s >>= 1) {
        if (t < s) fred[t] += fred[t + s];
        __syncthreads();
    }
    float nsum = fred[0];
    out[OFF_NCS + t] = ncs;
    cs_ws[t] = (ncs + EPSF) / (nsum + 1024.f * EPSF) * nsum;
    if (t == 0) out[OFF_LOSS] = CCOST * loss[0] / (float)NELEM;
}

// R27: block-aggregated scatter (Guideline 12). LDS hist+rank, one global
// atomic per distinct k per block, conflict-free perm writes.
__global__ void __launch_bounds__(256) scatter_kernel(
    const int* __restrict__ idxi, int* __restrict__ cursor,
    unsigned* __restrict__ perm) {
    __shared__ int lhist[1024];
    __shared__ int lbase[1024];
    int tid = threadIdx.x;
#pragma unroll
    for (int i = 0; i < 4; ++i) lhist[i * 256 + tid] = 0;
    __syncthreads();
    int n = blockIdx.x * 256 + tid;
    int k = idxi[n];
    int rank = atomicAdd(&lhist[k], 1);
    __syncthreads();
#pragma unroll
    for (int i = 0; i < 4; ++i) {
        int kk = i * 256 + tid;
        int c = lhist[kk];
        if (c > 0) lbase[kk] = atomicAdd(&cursor[kk], c);
    }
    __syncthreads();
    perm[lbase[k] + rank] = ((unsigned)k << 17) | (unsigned)n;  // k:10b, n:17b
}

// Balanced segmented reduction over sorted perm; wave = 32 entries.
__global__ void __launch_bounds__(256) dw_accum_kernel(
    const float* __restrict__ in, const float* __restrict__ xT,
    const unsigned* __restrict__ perm, float* __restrict__ dwT) {
    int t = threadIdx.x;
    int c = t & 63;
    int wv = t >> 6;
    int base = (blockIdx.x * 4 + wv) * 32;  // 2048 waves x 32 = 65536

    __shared__ unsigned spm[4][32];
    if (c < 32) spm[wv][c] = perm[base + c];
    __syncthreads();

    float acc = 0.f;
    unsigned cur = spm[wv][0] >> 17;
#pragma unroll 4
    for (int i = 0; i < 32; ++i) {
        unsigned e = spm[wv][i];  // broadcast
        unsigned k = e >> 17;
        unsigned n = e & 0x1FFFFu;
        if (k != cur) {  // wave-uniform
            atomicAdd(&dwT[cur * 64 + c], acc);
            acc = 0.f;
            cur = k;
        }
        if (xT) {
            acc += xT[(size_t)n * 64 + c];  // 256B contiguous per wave
        } else {
            acc += in[(size_t)(n >> 12) * 262144 + c * 4096 + (n & 4095)];
        }
    }
    atomicAdd(&dwT[cur * 64 + c], acc);
}

__global__ void __launch_bounds__(256) ema2_kernel(
    const float* __restrict__ embed_avg, const float* __restrict__ dwT,
    const float* __restrict__ cs_ws, float* __restrict__ out) {
    int i = blockIdx.x * 256 + threadIdx.x;  // i = c*K + k
    int k = i & (K - 1);
    int c = i >> 10;
    float avg = embed_avg[i] * DECAYF + OMDF * dwT[k * 64 + c];
    out[OFF_AVG + i] = avg;
    out[OFF_EMB + i] = avg / cs_ws[k];
}

extern "C" void kernel_launch(void* const* d_in, const int* in_sizes, int n_in,
                              void* d_out, int out_size, void* d_ws, size_t ws_size,
                              hipStream_t stream) {
    const float* in = (const float*)d_in[0];
    const float* E = (const float*)d_in[1];
    const float* cluster_size = (const float*)d_in[2];
    const float* embed_avg = (const float*)d_in[3];
    float* out = (float*)d_out;
    float* ws = (float*)d_ws;

    float* loss = ws;
    float* e2 = ws + 64;
    float* cs = ws + 1088;
    int* cursor = (int*)(ws + 2112);   // 1024
    int* hist = (int*)(ws + 3136);     // 1024
    int* idxi = (int*)(ws + 4224);     // 65536
    unsigned* perm = (unsigned*)(ws + 69760);  // 65536
    _Float16* Ef = (_Float16*)(ws + 135296);   // 131072 halves
    float* dwT = ws + 266368;          // 65536 ([K][64])
    float* ET = ws + 331904;           // 65536 ([K][64])
    float* xT = (ws_size >= (397440ull + 4194304ull) * 4ull) ? (ws + 397440) : nullptr;

    prep_kernel<<<K / 64, 256, 0, stream>>>(E, ET, e2, Ef, hist, loss, dwT);
    score_kernel<<<1024, 512, 0, stream>>>(in, Ef, ET, e2, out, idxi, xT, loss, hist);
    scan_kernel<<<1, 1024, 0, stream>>>(hist, cluster_size, loss, out, cs, cursor);
    scatter_kernel<<<NPOS / 256, 256, 0, stream>>>(idxi, cursor, perm);
    dw_accum_kernel<<<512, 256, 0, stream>>>(in, xT, perm, dwT);
    ema2_kernel<<<D * K / 256, 256, 0, stream>>>(embed_avg, dwT, cs, out);
}